// Round 1
// baseline (569.405 us; speedup 1.0000x reference)
//
#include <hip/hip_runtime.h>

typedef __attribute__((ext_vector_type(8))) short bf16x8;
typedef __attribute__((ext_vector_type(8))) unsigned short u16x8;
typedef __attribute__((ext_vector_type(4))) float f32x4;

#define MFMA16(a, b, c) __builtin_amdgcn_mfma_f32_16x16x32_bf16((a), (b), (c), 0, 0, 0)

__device__ __forceinline__ unsigned short f2bf(float f) {
  union { float f; unsigned u; } x; x.f = f;
  unsigned r = x.u + 0x7FFFu + ((x.u >> 16) & 1u);
  return (unsigned short)(r >> 16);
}
__device__ __forceinline__ float bf2f(unsigned short b) {
  union { unsigned u; float f; } x; x.u = ((unsigned)b) << 16;
  return x.f;
}

// ---------------- GEMM1: qkv = x @ qkv_w.T  -> scatter to Q/K/V [BH][N][D] bf16
__global__ __launch_bounds__(256) void qkv_gemm(const float* __restrict__ X,
                                                const float* __restrict__ W,
                                                unsigned short* __restrict__ Qo,
                                                unsigned short* __restrict__ Ko,
                                                unsigned short* __restrict__ Vo) {
  __shared__ unsigned short As[128][64];
  __shared__ unsigned short Bs[128][64];
  const int tid = threadIdx.x;
  const int lane = tid & 63, wave = tid >> 6;
  const int lrow = lane & 15, lgrp = lane >> 4;
  const int wr = wave >> 1, wc = wave & 1;
  const int m0 = blockIdx.x * 128, n0 = blockIdx.y * 128;

  f32x4 acc[4][4];
#pragma unroll
  for (int i = 0; i < 4; i++)
#pragma unroll
    for (int j = 0; j < 4; j++) acc[i][j] = (f32x4){0.f, 0.f, 0.f, 0.f};

  const int sr = tid >> 1;
  const int sk = (tid & 1) * 32;

  for (int k0 = 0; k0 < 768; k0 += 64) {
    {
      const float4* sa = (const float4*)(X + (size_t)(m0 + sr) * 768 + k0 + sk);
      const float4* sb = (const float4*)(W + (size_t)(n0 + sr) * 768 + k0 + sk);
#pragma unroll
      for (int c = 0; c < 4; c++) {
        float4 f0 = sa[2 * c], f1 = sa[2 * c + 1];
        u16x8 va;
        va[0] = f2bf(f0.x); va[1] = f2bf(f0.y); va[2] = f2bf(f0.z); va[3] = f2bf(f0.w);
        va[4] = f2bf(f1.x); va[5] = f2bf(f1.y); va[6] = f2bf(f1.z); va[7] = f2bf(f1.w);
        *(u16x8*)(&As[sr][(((sk >> 3) + c) ^ (sr & 7)) << 3]) = va;
        float4 g0 = sb[2 * c], g1 = sb[2 * c + 1];
        u16x8 vb;
        vb[0] = f2bf(g0.x); vb[1] = f2bf(g0.y); vb[2] = f2bf(g0.z); vb[3] = f2bf(g0.w);
        vb[4] = f2bf(g1.x); vb[5] = f2bf(g1.y); vb[6] = f2bf(g1.z); vb[7] = f2bf(g1.w);
        *(u16x8*)(&Bs[sr][(((sk >> 3) + c) ^ (sr & 7)) << 3]) = vb;
      }
    }
    __syncthreads();
#pragma unroll
    for (int kk = 0; kk < 2; kk++) {
      bf16x8 a[4], b[4];
#pragma unroll
      for (int f = 0; f < 4; f++) {
        int ra = wr * 64 + f * 16 + lrow;
        a[f] = *(const bf16x8*)(&As[ra][((kk * 4 + lgrp) ^ (ra & 7)) << 3]);
        int rb = wc * 64 + f * 16 + lrow;
        b[f] = *(const bf16x8*)(&Bs[rb][((kk * 4 + lgrp) ^ (rb & 7)) << 3]);
      }
#pragma unroll
      for (int i = 0; i < 4; i++)
#pragma unroll
        for (int j = 0; j < 4; j++) acc[i][j] = MFMA16(a[i], b[j], acc[i][j]);
    }
    __syncthreads();
  }

#pragma unroll
  for (int fj = 0; fj < 4; fj++) {
    const int jb = n0 + wc * 64 + fj * 16;
    const int s = jb / 768;
    const int hh = (jb % 768) >> 6;
    const int dd = (jb & 63) + lrow;
    unsigned short* dst = (s == 0) ? Qo : (s == 1) ? Ko : Vo;
#pragma unroll
    for (int fi = 0; fi < 4; fi++) {
#pragma unroll
      for (int r = 0; r < 4; r++) {
        int m = m0 + wr * 64 + fi * 16 + lgrp * 4 + r;
        int bb = m / 197;
        int nn = m - bb * 197;
        dst[(size_t)((bb * 12 + hh) * 197 + nn) * 64 + dd] = f2bf(acc[fi][fj][r]);
      }
    }
  }
}

// ---------------- Attention: per (b,h) block; dist-attn with pi weighting ----
__global__ __launch_bounds__(256) void attn_kernel(const unsigned short* __restrict__ Q,
                                                   const unsigned short* __restrict__ K,
                                                   const unsigned short* __restrict__ V,
                                                   const float* __restrict__ piq,
                                                   const float* __restrict__ pik,
                                                   unsigned short* __restrict__ Oa) {
  __shared__ unsigned short Qs[208][64];
  __shared__ unsigned short Ks[208][64];
  __shared__ unsigned short Vt[64][232];
  __shared__ unsigned short Ps[4][16][232];
  __shared__ float q2s[208], k2s[208], piqs[208], piks_[208];

  const int tid = threadIdx.x;
  const int lane = tid & 63, wave = tid >> 6;
  const int lrow = lane & 15, lgrp = lane >> 4;
  const int bh = blockIdx.x;
  const int h = bh % 12;
  const int b = bh / 12;

  {
    uint4 z = {0u, 0u, 0u, 0u};
    for (int i = tid; i < 1664; i += 256) { ((uint4*)Qs)[i] = z; ((uint4*)Ks)[i] = z; }
    for (int i = tid; i < 1856; i += 256) { ((uint4*)Vt)[i] = z; ((uint4*)Ps)[i] = z; }
  }
  __syncthreads();

  if (tid < 208) {
    const int n = tid;
    const bool valid = n < 197;
    float q2 = 0.f, k2 = 0.f;
    if (valid) {
      const size_t base = ((size_t)bh * 197 + n) * 64;
#pragma unroll
      for (int c = 0; c < 8; c++) {
        u16x8 vq = *(const u16x8*)(Q + base + c * 8);
        u16x8 vk = *(const u16x8*)(K + base + c * 8);
#pragma unroll
        for (int e = 0; e < 8; e++) {
          float fq = bf2f((unsigned short)vq[e]); q2 += fq * fq;
          float fk = bf2f((unsigned short)vk[e]); k2 += fk * fk;
        }
        int cs = c ^ (n & 7);
        *(u16x8*)(&Qs[n][cs << 3]) = vq;
        *(u16x8*)(&Ks[n][cs << 3]) = vk;
      }
#pragma unroll
      for (int c = 0; c < 8; c++) {
        u16x8 vv = *(const u16x8*)(V + base + c * 8);
#pragma unroll
        for (int e = 0; e < 8; e++) Vt[c * 8 + e][n] = (unsigned short)vv[e];
      }
    }
    q2s[n] = valid ? q2 : 0.f;
    k2s[n] = valid ? k2 : 1e30f;
    piqs[n] = valid ? fminf(fabsf(piq[h * 197 + n]), 1.f) : 0.f;
    piks_[n] = valid ? fminf(fabsf(pik[h * 197 + n]), 1.f) : 0.f;
  }
  __syncthreads();

  for (int t = wave; t < 13; t += 4) {
    const int n0 = t * 16;
    bf16x8 aq[2];
    {
      const int rq = n0 + lrow;
      aq[0] = *(const bf16x8*)(&Qs[rq][((0 + lgrp) ^ (rq & 7)) << 3]);
      aq[1] = *(const bf16x8*)(&Qs[rq][((4 + lgrp) ^ (rq & 7)) << 3]);
    }
    float rs[4] = {0.f, 0.f, 0.f, 0.f};
    float q2r[4];
#pragma unroll
    for (int r = 0; r < 4; r++) q2r[r] = q2s[n0 + lgrp * 4 + r];

    for (int jt = 0; jt < 13; jt++) {
      f32x4 sacc = (f32x4){0.f, 0.f, 0.f, 0.f};
      const int rk = jt * 16 + lrow;
      bf16x8 bk0 = *(const bf16x8*)(&Ks[rk][((0 + lgrp) ^ (rk & 7)) << 3]);
      bf16x8 bk1 = *(const bf16x8*)(&Ks[rk][((4 + lgrp) ^ (rk & 7)) << 3]);
      sacc = MFMA16(aq[0], bk0, sacc);
      sacc = MFMA16(aq[1], bk1, sacc);
      const int j = jt * 16 + lrow;
      const float k2j = k2s[j];
      const float pikj = piks_[j];
#pragma unroll
      for (int r = 0; r < 4; r++) {
        float sq = q2r[r] + k2j - 2.f * sacc[r];
        sq = fmaxf(sq, 0.f);
        float p = __expf(-0.0625f * sq) * pikj;
        rs[r] += p;
        Ps[wave][lgrp * 4 + r][j] = f2bf(p);
      }
    }
#pragma unroll
    for (int r = 0; r < 4; r++) {
      float v = rs[r];
      v += __shfl_xor(v, 1);
      v += __shfl_xor(v, 2);
      v += __shfl_xor(v, 4);
      v += __shfl_xor(v, 8);
      rs[r] = v;
    }
    float scale[4];
#pragma unroll
    for (int r = 0; r < 4; r++) {
      float pq = piqs[n0 + lgrp * 4 + r];
      scale[r] = pq / (pq * rs[r] + 1e-6f);
    }
    f32x4 o[4];
#pragma unroll
    for (int dt = 0; dt < 4; dt++) o[dt] = (f32x4){0.f, 0.f, 0.f, 0.f};
#pragma unroll
    for (int ks = 0; ks < 7; ks++) {
      bf16x8 ap = *(const bf16x8*)(&Ps[wave][lrow][ks * 32 + lgrp * 8]);
#pragma unroll
      for (int dt = 0; dt < 4; dt++) {
        bf16x8 bv = *(const bf16x8*)(&Vt[dt * 16 + lrow][ks * 32 + lgrp * 8]);
        o[dt] = MFMA16(ap, bv, o[dt]);
      }
    }
#pragma unroll
    for (int r = 0; r < 4; r++) {
      const int n = n0 + lgrp * 4 + r;
      if (n < 197) {
        const size_t ob = ((size_t)(b * 197 + n)) * 768 + h * 64;
#pragma unroll
        for (int dt = 0; dt < 4; dt++) Oa[ob + dt * 16 + lrow] = f2bf(o[dt][r] * scale[r]);
      }
    }
  }
}

// ---------------- GEMM3: out = att @ proj_w.T + proj_b  (fp32 out) ----------
__global__ __launch_bounds__(256) void proj_gemm(const unsigned short* __restrict__ A,
                                                 const float* __restrict__ W,
                                                 const float* __restrict__ bias,
                                                 float* __restrict__ out) {
  __shared__ unsigned short As[128][64];
  __shared__ unsigned short Bs[128][64];
  const int tid = threadIdx.x;
  const int lane = tid & 63, wave = tid >> 6;
  const int lrow = lane & 15, lgrp = lane >> 4;
  const int wr = wave >> 1, wc = wave & 1;
  const int m0 = blockIdx.x * 128, n0 = blockIdx.y * 128;

  f32x4 acc[4][4];
#pragma unroll
  for (int i = 0; i < 4; i++)
#pragma unroll
    for (int j = 0; j < 4; j++) acc[i][j] = (f32x4){0.f, 0.f, 0.f, 0.f};

  const int sr = tid >> 1;
  const int sk = (tid & 1) * 32;

  for (int k0 = 0; k0 < 768; k0 += 64) {
    {
      const u16x8* sa = (const u16x8*)(A + (size_t)(m0 + sr) * 768 + k0 + sk);
      const float4* sb = (const float4*)(W + (size_t)(n0 + sr) * 768 + k0 + sk);
#pragma unroll
      for (int c = 0; c < 4; c++) {
        u16x8 va = sa[c];
        *(u16x8*)(&As[sr][(((sk >> 3) + c) ^ (sr & 7)) << 3]) = va;
        float4 g0 = sb[2 * c], g1 = sb[2 * c + 1];
        u16x8 vb;
        vb[0] = f2bf(g0.x); vb[1] = f2bf(g0.y); vb[2] = f2bf(g0.z); vb[3] = f2bf(g0.w);
        vb[4] = f2bf(g1.x); vb[5] = f2bf(g1.y); vb[6] = f2bf(g1.z); vb[7] = f2bf(g1.w);
        *(u16x8*)(&Bs[sr][(((sk >> 3) + c) ^ (sr & 7)) << 3]) = vb;
      }
    }
    __syncthreads();
#pragma unroll
    for (int kk = 0; kk < 2; kk++) {
      bf16x8 a[4], b[4];
#pragma unroll
      for (int f = 0; f < 4; f++) {
        int ra = wr * 64 + f * 16 + lrow;
        a[f] = *(const bf16x8*)(&As[ra][((kk * 4 + lgrp) ^ (ra & 7)) << 3]);
        int rb = wc * 64 + f * 16 + lrow;
        b[f] = *(const bf16x8*)(&Bs[rb][((kk * 4 + lgrp) ^ (rb & 7)) << 3]);
      }
#pragma unroll
      for (int i = 0; i < 4; i++)
#pragma unroll
        for (int j = 0; j < 4; j++) acc[i][j] = MFMA16(a[i], b[j], acc[i][j]);
    }
    __syncthreads();
  }

#pragma unroll
  for (int fj = 0; fj < 4; fj++) {
    const int j = n0 + wc * 64 + fj * 16 + lrow;
    const float bj = bias[j];
#pragma unroll
    for (int fi = 0; fi < 4; fi++) {
#pragma unroll
      for (int r = 0; r < 4; r++) {
        int m = m0 + wr * 64 + fi * 16 + lgrp * 4 + r;
        out[(size_t)m * 768 + j] = acc[fi][fj][r] + bj;
      }
    }
  }
}

extern "C" void kernel_launch(void* const* d_in, const int* in_sizes, int n_in,
                              void* d_out, int out_size, void* d_ws, size_t ws_size,
                              hipStream_t stream) {
  const float* x = (const float*)d_in[0];
  const float* qkv_w = (const float*)d_in[1];
  const float* proj_w = (const float*)d_in[2];
  const float* proj_b = (const float*)d_in[3];
  const float* pi_q = (const float*)d_in[4];
  const float* pi_k = (const float*)d_in[5];
  float* out = (float*)d_out;

  unsigned short* ws = (unsigned short*)d_ws;
  const size_t S = (size_t)1536 * 197 * 64;  // 19,365,888 elems per tensor
  unsigned short* Q = ws;
  unsigned short* K = ws + S;
  unsigned short* V = ws + 2 * S;
  unsigned short* Oa = ws + 3 * S;

  dim3 blk(256, 1, 1);
  qkv_gemm<<<dim3(197, 18, 1), blk, 0, stream>>>(x, qkv_w, Q, K, V);
  attn_kernel<<<dim3(1536, 1, 1), blk, 0, stream>>>(Q, K, V, pi_q, pi_k, Oa);
  proj_gemm<<<dim3(197, 6, 1), blk, 0, stream>>>(Oa, proj_w, proj_b, out);
}

// Round 2
// 346.638 us; speedup vs baseline: 1.6426x; 1.6426x over previous
//
#include <hip/hip_runtime.h>

typedef __attribute__((ext_vector_type(8))) short bf16x8;
typedef __attribute__((ext_vector_type(8))) unsigned short u16x8;
typedef __attribute__((ext_vector_type(4))) float f32x4;

#define MFMA16(a, b, c) __builtin_amdgcn_mfma_f32_16x16x32_bf16((a), (b), (c), 0, 0, 0)

__device__ __forceinline__ unsigned short f2bf(float f) {
  union { float f; unsigned u; } x; x.f = f;
  unsigned r = x.u + 0x7FFFu + ((x.u >> 16) & 1u);
  return (unsigned short)(r >> 16);
}
__device__ __forceinline__ float bf2f(unsigned short b) {
  union { unsigned u; float f; } x; x.u = ((unsigned)b) << 16;
  return x.f;
}

__device__ __forceinline__ void gld_lds16(const void* g, void* l) {
  __builtin_amdgcn_global_load_lds(
      (const __attribute__((address_space(1))) unsigned int*)g,
      (__attribute__((address_space(3))) unsigned int*)l, 16, 0, 0);
}

// ---------------- fp32 -> bf16 bulk convert (memory-bound) ------------------
__global__ __launch_bounds__(256) void cvt_kernel(const float* __restrict__ s,
                                                  unsigned short* __restrict__ d,
                                                  int n8) {
  int i = blockIdx.x * 256 + threadIdx.x;
  const int stride = gridDim.x * 256;
  for (; i < n8; i += stride) {
    float4 f0 = ((const float4*)s)[2 * i];
    float4 f1 = ((const float4*)s)[2 * i + 1];
    u16x8 v;
    v[0] = f2bf(f0.x); v[1] = f2bf(f0.y); v[2] = f2bf(f0.z); v[3] = f2bf(f0.w);
    v[4] = f2bf(f1.x); v[5] = f2bf(f1.y); v[6] = f2bf(f1.z); v[7] = f2bf(f1.w);
    ((u16x8*)d)[i] = v;
  }
}

// ---------------- GEMM1: qkv = Xb @ Wb.T -> scatter to Q/K/V [BH][N][D] bf16
// m97 structure: 128x128 tile, BK=64, global_load_lds width-16, linear LDS.
__global__ __launch_bounds__(256) void qkv_gemm(const unsigned short* __restrict__ X,
                                                const unsigned short* __restrict__ W,
                                                unsigned short* __restrict__ Qo,
                                                unsigned short* __restrict__ Ko,
                                                unsigned short* __restrict__ Vo) {
  __shared__ unsigned short As[128][64];
  __shared__ unsigned short Bs[128][64];
  const int tid = threadIdx.x;
  const int lane = tid & 63, wave = tid >> 6;
  const int lrow = lane & 15, lgrp = lane >> 4;
  const int wr = wave >> 1, wc = wave & 1;
  const int m0 = blockIdx.x * 128, n0 = blockIdx.y * 128;

  f32x4 acc[4][4];
#pragma unroll
  for (int i = 0; i < 4; i++)
#pragma unroll
    for (int j = 0; j < 4; j++) acc[i][j] = (f32x4){0.f, 0.f, 0.f, 0.f};

  const int rbase = wave * 32;
  const int srow = rbase + (lane >> 3);
  const int scol = (lane & 7) * 8;

  for (int k0 = 0; k0 < 768; k0 += 64) {
    const unsigned short* ga = X + (size_t)(m0 + srow) * 768 + k0 + scol;
    const unsigned short* gb = W + (size_t)(n0 + srow) * 768 + k0 + scol;
#pragma unroll
    for (int i = 0; i < 4; i++) {
      gld_lds16(ga + (size_t)i * 8 * 768, &As[rbase + i * 8][0]);
      gld_lds16(gb + (size_t)i * 8 * 768, &Bs[rbase + i * 8][0]);
    }
    __syncthreads();
#pragma unroll
    for (int kk = 0; kk < 2; kk++) {
      bf16x8 a[4], b[4];
#pragma unroll
      for (int f = 0; f < 4; f++) {
        a[f] = *(const bf16x8*)(&As[wr * 64 + f * 16 + lrow][kk * 32 + lgrp * 8]);
        b[f] = *(const bf16x8*)(&Bs[wc * 64 + f * 16 + lrow][kk * 32 + lgrp * 8]);
      }
#pragma unroll
      for (int i = 0; i < 4; i++)
#pragma unroll
        for (int j = 0; j < 4; j++) acc[i][j] = MFMA16(a[i], b[j], acc[i][j]);
    }
    __syncthreads();
  }

#pragma unroll
  for (int fj = 0; fj < 4; fj++) {
    const int jb = n0 + wc * 64 + fj * 16;
    const int s = jb / 768;
    const int hh = (jb % 768) >> 6;
    const int dd = (jb & 63) + lrow;
    unsigned short* dst = (s == 0) ? Qo : (s == 1) ? Ko : Vo;
#pragma unroll
    for (int fi = 0; fi < 4; fi++) {
#pragma unroll
      for (int r = 0; r < 4; r++) {
        int m = m0 + wr * 64 + fi * 16 + lgrp * 4 + r;
        int bb = m / 197;
        int nn = m - bb * 197;
        dst[(size_t)((bb * 12 + hh) * 197 + nn) * 64 + dd] = f2bf(acc[fi][fj][r]);
      }
    }
  }
}

// ---------------- Attention: per (b,h) block; dist-attn with pi weighting ----
__global__ __launch_bounds__(256) void attn_kernel(const unsigned short* __restrict__ Q,
                                                   const unsigned short* __restrict__ K,
                                                   const unsigned short* __restrict__ V,
                                                   const float* __restrict__ piq,
                                                   const float* __restrict__ pik,
                                                   unsigned short* __restrict__ Oa) {
  __shared__ unsigned short Qs[208][64];
  __shared__ unsigned short Ks[208][64];
  __shared__ unsigned short Vt[64][232];
  __shared__ unsigned short Ps[4][16][232];
  __shared__ float q2s[208], k2s[208], piqs[208], piks_[208];

  const int tid = threadIdx.x;
  const int lane = tid & 63, wave = tid >> 6;
  const int lrow = lane & 15, lgrp = lane >> 4;
  const int bh = blockIdx.x;
  const int h = bh % 12;
  const int b = bh / 12;

  {
    uint4 z = {0u, 0u, 0u, 0u};
    for (int i = tid; i < 1664; i += 256) { ((uint4*)Qs)[i] = z; ((uint4*)Ks)[i] = z; }
    for (int i = tid; i < 1856; i += 256) { ((uint4*)Vt)[i] = z; ((uint4*)Ps)[i] = z; }
  }
  __syncthreads();

  if (tid < 208) {
    const int n = tid;
    const bool valid = n < 197;
    float q2 = 0.f, k2 = 0.f;
    if (valid) {
      const size_t base = ((size_t)bh * 197 + n) * 64;
#pragma unroll
      for (int c = 0; c < 8; c++) {
        u16x8 vq = *(const u16x8*)(Q + base + c * 8);
        u16x8 vk = *(const u16x8*)(K + base + c * 8);
#pragma unroll
        for (int e = 0; e < 8; e++) {
          float fq = bf2f((unsigned short)vq[e]); q2 += fq * fq;
          float fk = bf2f((unsigned short)vk[e]); k2 += fk * fk;
        }
        int cs = c ^ (n & 7);
        *(u16x8*)(&Qs[n][cs << 3]) = vq;
        *(u16x8*)(&Ks[n][cs << 3]) = vk;
      }
#pragma unroll
      for (int c = 0; c < 8; c++) {
        u16x8 vv = *(const u16x8*)(V + base + c * 8);
#pragma unroll
        for (int e = 0; e < 8; e++) Vt[c * 8 + e][n] = (unsigned short)vv[e];
      }
    }
    q2s[n] = valid ? q2 : 0.f;
    k2s[n] = valid ? k2 : 1e30f;
    piqs[n] = valid ? fminf(fabsf(piq[h * 197 + n]), 1.f) : 0.f;
    piks_[n] = valid ? fminf(fabsf(pik[h * 197 + n]), 1.f) : 0.f;
  }
  __syncthreads();

  for (int t = wave; t < 13; t += 4) {
    const int n0 = t * 16;
    bf16x8 aq[2];
    {
      const int rq = n0 + lrow;
      aq[0] = *(const bf16x8*)(&Qs[rq][((0 + lgrp) ^ (rq & 7)) << 3]);
      aq[1] = *(const bf16x8*)(&Qs[rq][((4 + lgrp) ^ (rq & 7)) << 3]);
    }
    float rs[4] = {0.f, 0.f, 0.f, 0.f};
    float q2r[4];
#pragma unroll
    for (int r = 0; r < 4; r++) q2r[r] = q2s[n0 + lgrp * 4 + r];

    for (int jt = 0; jt < 13; jt++) {
      f32x4 sacc = (f32x4){0.f, 0.f, 0.f, 0.f};
      const int rk = jt * 16 + lrow;
      bf16x8 bk0 = *(const bf16x8*)(&Ks[rk][((0 + lgrp) ^ (rk & 7)) << 3]);
      bf16x8 bk1 = *(const bf16x8*)(&Ks[rk][((4 + lgrp) ^ (rk & 7)) << 3]);
      sacc = MFMA16(aq[0], bk0, sacc);
      sacc = MFMA16(aq[1], bk1, sacc);
      const int j = jt * 16 + lrow;
      const float k2j = k2s[j];
      const float pikj = piks_[j];
#pragma unroll
      for (int r = 0; r < 4; r++) {
        float sq = q2r[r] + k2j - 2.f * sacc[r];
        sq = fmaxf(sq, 0.f);
        float p = __expf(-0.0625f * sq) * pikj;
        rs[r] += p;
        Ps[wave][lgrp * 4 + r][j] = f2bf(p);
      }
    }
#pragma unroll
    for (int r = 0; r < 4; r++) {
      float v = rs[r];
      v += __shfl_xor(v, 1);
      v += __shfl_xor(v, 2);
      v += __shfl_xor(v, 4);
      v += __shfl_xor(v, 8);
      rs[r] = v;
    }
    float scale[4];
#pragma unroll
    for (int r = 0; r < 4; r++) {
      float pq = piqs[n0 + lgrp * 4 + r];
      scale[r] = pq / (pq * rs[r] + 1e-6f);
    }
    f32x4 o[4];
#pragma unroll
    for (int dt = 0; dt < 4; dt++) o[dt] = (f32x4){0.f, 0.f, 0.f, 0.f};
#pragma unroll
    for (int ks = 0; ks < 7; ks++) {
      bf16x8 ap = *(const bf16x8*)(&Ps[wave][lrow][ks * 32 + lgrp * 8]);
#pragma unroll
      for (int dt = 0; dt < 4; dt++) {
        bf16x8 bv = *(const bf16x8*)(&Vt[dt * 16 + lrow][ks * 32 + lgrp * 8]);
        o[dt] = MFMA16(ap, bv, o[dt]);
      }
    }
#pragma unroll
    for (int r = 0; r < 4; r++) {
      const int n = n0 + lgrp * 4 + r;
      if (n < 197) {
        const size_t ob = ((size_t)(b * 197 + n)) * 768 + h * 64;
#pragma unroll
        for (int dt = 0; dt < 4; dt++) Oa[ob + dt * 16 + lrow] = f2bf(o[dt][r] * scale[r]);
      }
    }
  }
}

// ---------------- GEMM3: out = Oa @ Pb.T + proj_b  (fp32 out) ---------------
__global__ __launch_bounds__(256) void proj_gemm(const unsigned short* __restrict__ A,
                                                 const unsigned short* __restrict__ W,
                                                 const float* __restrict__ bias,
                                                 float* __restrict__ out) {
  __shared__ unsigned short As[128][64];
  __shared__ unsigned short Bs[128][64];
  const int tid = threadIdx.x;
  const int lane = tid & 63, wave = tid >> 6;
  const int lrow = lane & 15, lgrp = lane >> 4;
  const int wr = wave >> 1, wc = wave & 1;
  const int m0 = blockIdx.x * 128, n0 = blockIdx.y * 128;

  f32x4 acc[4][4];
#pragma unroll
  for (int i = 0; i < 4; i++)
#pragma unroll
    for (int j = 0; j < 4; j++) acc[i][j] = (f32x4){0.f, 0.f, 0.f, 0.f};

  const int rbase = wave * 32;
  const int srow = rbase + (lane >> 3);
  const int scol = (lane & 7) * 8;

  for (int k0 = 0; k0 < 768; k0 += 64) {
    const unsigned short* ga = A + (size_t)(m0 + srow) * 768 + k0 + scol;
    const unsigned short* gb = W + (size_t)(n0 + srow) * 768 + k0 + scol;
#pragma unroll
    for (int i = 0; i < 4; i++) {
      gld_lds16(ga + (size_t)i * 8 * 768, &As[rbase + i * 8][0]);
      gld_lds16(gb + (size_t)i * 8 * 768, &Bs[rbase + i * 8][0]);
    }
    __syncthreads();
#pragma unroll
    for (int kk = 0; kk < 2; kk++) {
      bf16x8 a[4], b[4];
#pragma unroll
      for (int f = 0; f < 4; f++) {
        a[f] = *(const bf16x8*)(&As[wr * 64 + f * 16 + lrow][kk * 32 + lgrp * 8]);
        b[f] = *(const bf16x8*)(&Bs[wc * 64 + f * 16 + lrow][kk * 32 + lgrp * 8]);
      }
#pragma unroll
      for (int i = 0; i < 4; i++)
#pragma unroll
        for (int j = 0; j < 4; j++) acc[i][j] = MFMA16(a[i], b[j], acc[i][j]);
    }
    __syncthreads();
  }

#pragma unroll
  for (int fj = 0; fj < 4; fj++) {
    const int j = n0 + wc * 64 + fj * 16 + lrow;
    const float bj = bias[j];
#pragma unroll
    for (int fi = 0; fi < 4; fi++) {
#pragma unroll
      for (int r = 0; r < 4; r++) {
        int m = m0 + wr * 64 + fi * 16 + lgrp * 4 + r;
        out[(size_t)m * 768 + j] = acc[fi][fj][r] + bj;
      }
    }
  }
}

extern "C" void kernel_launch(void* const* d_in, const int* in_sizes, int n_in,
                              void* d_out, int out_size, void* d_ws, size_t ws_size,
                              hipStream_t stream) {
  const float* x = (const float*)d_in[0];
  const float* qkv_w = (const float*)d_in[1];
  const float* proj_w = (const float*)d_in[2];
  const float* proj_b = (const float*)d_in[3];
  const float* pi_q = (const float*)d_in[4];
  const float* pi_k = (const float*)d_in[5];
  float* out = (float*)d_out;

  unsigned short* ws = (unsigned short*)d_ws;
  const size_t S = (size_t)1536 * 197 * 64;  // 19,365,888 elems per tensor
  unsigned short* Q = ws;
  unsigned short* K = ws + S;
  unsigned short* V = ws + 2 * S;
  unsigned short* Xb = ws + 3 * S;   // aliased: Oa reuses this region after qkv
  unsigned short* Oa = Xb;
  unsigned short* Wb = ws + 4 * S;                 // 2304*768 bf16
  unsigned short* Pb = Wb + (size_t)2304 * 768;    // 768*768 bf16

  dim3 blk(256, 1, 1);
  cvt_kernel<<<dim3(2048, 1, 1), blk, 0, stream>>>(x, Xb, 2420736);
  cvt_kernel<<<dim3(864, 1, 1), blk, 0, stream>>>(qkv_w, Wb, 221184);
  cvt_kernel<<<dim3(288, 1, 1), blk, 0, stream>>>(proj_w, Pb, 73728);
  qkv_gemm<<<dim3(197, 18, 1), blk, 0, stream>>>(Xb, Wb, Q, K, V);
  attn_kernel<<<dim3(1536, 1, 1), blk, 0, stream>>>(Q, K, V, pi_q, pi_k, Oa);
  proj_gemm<<<dim3(197, 6, 1), blk, 0, stream>>>(Oa, Pb, proj_b, out);
}